// Round 18
// baseline (169.123 us; speedup 1.0000x reference)
//
#include <hip/hip_runtime.h>
#include <stdint.h>

typedef unsigned int u32;
typedef unsigned long long u64;
typedef unsigned short u16;
typedef __attribute__((ext_vector_type(8))) __bf16 bf16x8;
typedef __attribute__((ext_vector_type(4))) float f32x4;

#define DEV __device__ __forceinline__

DEV u16 f2bf(float f) {
    u32 x = __builtin_bit_cast(u32, f);
    u32 r = (x + 0x7FFFu + ((x >> 16) & 1u)) >> 16;
    return (u16)r;
}

DEV float bf2f(u16 x) {
    u32 u = (u32)x << 16;
    return __builtin_bit_cast(float, u);
}

DEV void unp8(uint4 u, float* f) {
    f[0] = bf2f((u16)u.x); f[1] = bf2f((u16)(u.x >> 16));
    f[2] = bf2f((u16)u.y); f[3] = bf2f((u16)(u.y >> 16));
    f[4] = bf2f((u16)u.z); f[5] = bf2f((u16)(u.z >> 16));
    f[6] = bf2f((u16)u.w); f[7] = bf2f((u16)(u.w >> 16));
}

DEV bf16x8 ldg8(const u16* p) {
    return __builtin_bit_cast(bf16x8, *(const uint4*)p);
}

DEV u32 pk2(float a, float b) {
    return (u32)f2bf(a) | ((u32)f2bf(b) << 16);
}

DEV float ex2(float x) {
    return __builtin_amdgcn_exp2f(x);
}

DEV void g2l16(const u16* g, u16* l) {
    __builtin_amdgcn_global_load_lds(
        (const __attribute__((address_space(1))) u32*)g,
        (__attribute__((address_space(3))) u32*)l, 16, 0, 0);
}

DEV f32x4 mfma16(bf16x8 a, bf16x8 b, f32x4 c) {
    return __builtin_amdgcn_mfma_f32_16x16x32_bf16(a, b, c, 0, 0, 0);
}

// ---------------------------------------------------------------- prologue
// sections: [0,10240) wtrans ; [10240,12288) prep ; [12288,16384) packmask
struct ProArgs {
    const float* w[10];
    u16* wtbase;
    const float4 *tgt, *tpos, *mem, *mpos;
    ushort4 *qin, *tgtb, *memb, *mkb, *tposb;
    const int4 *m1, *m2;
    u32 *o1, *o2;
};
__global__ __launch_bounds__(256) void prologue_kernel(ProArgs a) {
    const int bx = blockIdx.x, t = threadIdx.x;
    if (bx < 10240) {
        int z = bx >> 10, bxx = bx & 1023;
        int Kd = (z == 9) ? 2048 : 512;
        int Nd = (z == 8) ? 2048 : 512;
        size_t off = (z < 8) ? (size_t)z * 262144
                             : (z == 8 ? (size_t)2097152 : (size_t)3145728);
        u16* out = a.wtbase + off;
        int nx = Nd / 32;
        int txile = bxx % nx, tyile = bxx / nx;
        if (tyile >= Kd / 32) return;
        const float* w = a.w[z];
        __shared__ float tl[32][33];
        int tx = t & 31, ty = t >> 5;
#pragma unroll
        for (int j = 0; j < 4; ++j)
            tl[ty + j * 8][tx] = w[(size_t)(tyile * 32 + ty + j * 8) * Nd + txile * 32 + tx];
        __syncthreads();
#pragma unroll
        for (int j = 0; j < 4; ++j)
            out[(size_t)(txile * 32 + ty + j * 8) * Kd + tyile * 32 + tx] = f2bf(tl[tx][ty + j * 8]);
    } else if (bx < 12288) {
        int i = (bx - 10240) * 256 + t;
        float4 tt = a.tgt[i], p = a.tpos[i], m = a.mem[i], mp = a.mpos[i];
        a.qin[i]  = make_ushort4(f2bf(tt.x + p.x), f2bf(tt.y + p.y), f2bf(tt.z + p.z), f2bf(tt.w + p.w));
        a.tgtb[i] = make_ushort4(f2bf(tt.x), f2bf(tt.y), f2bf(tt.z), f2bf(tt.w));
        a.memb[i] = make_ushort4(f2bf(m.x), f2bf(m.y), f2bf(m.z), f2bf(m.w));
        a.mkb[i]  = make_ushort4(f2bf(m.x + mp.x), f2bf(m.y + mp.y), f2bf(m.z + mp.z), f2bf(m.w + mp.w));
        a.tposb[i]= make_ushort4(f2bf(p.x), f2bf(p.y), f2bf(p.z), f2bf(p.w));
    } else {
        int i = (bx - 12288) * 256 + t;
        const int n8 = 524288;
        bool first = i < n8;
        int idx = first ? i : i - n8;
        const int4* src = first ? a.m1 : a.m2;
        int4 x = src[idx * 2], y = src[idx * 2 + 1];
        u32 by = (u32)(x.x != 0) | ((u32)(x.y != 0) << 1) | ((u32)(x.z != 0) << 2) |
                 ((u32)(x.w != 0) << 3) | ((u32)(y.x != 0) << 4) | ((u32)(y.y != 0) << 5) |
                 ((u32)(y.z != 0) << 6) | ((u32)(y.w != 0) << 7);
        u32 w = by | (__shfl_down(by, 1) << 8) | (__shfl_down(by, 2) << 16) |
                (__shfl_down(by, 3) << 24);
        if ((t & 3) == 0) (first ? a.o1 : a.o2)[idx >> 2] = w;
    }
}

// ---------------------------------------------------------------- GEMM (double-buffered staging)
// C[M][N] = (A[M][k0:k0+klen] @ W^T[N][k0:k0+klen] + bias?) * oscale -> bf16
// epi: 0 bf16, 1 bf16+relu, 3 bf16 V-transposed -> VT[b*8+h][d][s] (S=1024)
struct GemmSet {
    const u16* A; const u16* W; const float* bias; void* out;
    float oscale; int epi; int k0; int klen;
};
struct GemmArgs5 { GemmSet s[5]; };

template <int BM, int BN>
__global__ __launch_bounds__(256) void gemm_kernel(GemmArgs5 args, int M, int N, int Kd) {
    constexpr int MF = BM / 32, NF = BN / 32;
    const GemmSet gs = args.s[blockIdx.z];
    const u16* __restrict__ A = gs.A;
    const u16* __restrict__ W = gs.W;
    const int t = threadIdx.x;
    const int lane = t & 63;
    const int g = lane >> 4, r16 = lane & 15;
    const int wave = t >> 6;
    const int wm = wave >> 1, wn = wave & 1;
    const int nwg = gridDim.x * gridDim.y;
    const int fid = blockIdx.y * gridDim.x + blockIdx.x;
    const int qq = nwg >> 3;
    const int lid = (fid & 7) * qq + (fid >> 3);
    const int m0 = (lid / gridDim.x) * BM, n0 = (lid % gridDim.x) * BN;

    __shared__ __align__(16) u16 As[2][BM * 64];
    __shared__ __align__(16) u16 Bs[2][BN * 64];

    f32x4 acc[MF][NF];
#pragma unroll
    for (int m = 0; m < MF; ++m)
#pragma unroll
        for (int n = 0; n < NF; ++n) acc[m][n] = f32x4{0.f, 0.f, 0.f, 0.f};

    const int nk = gs.klen >> 6;
    // stage chunk 0
    {
        const int kk = gs.k0;
#pragma unroll
        for (int i = 0; i < BM / 32; ++i) {
            int cid = t + i * 256, row = cid >> 3, c = cid & 7;
            g2l16(A + (size_t)(m0 + row) * Kd + kk + ((c ^ (row & 7)) << 3), &As[0][cid << 3]);
        }
#pragma unroll
        for (int i = 0; i < BN / 32; ++i) {
            int cid = t + i * 256, row = cid >> 3, c = cid & 7;
            g2l16(W + (size_t)(n0 + row) * Kd + kk + ((c ^ (row & 7)) << 3), &Bs[0][cid << 3]);
        }
    }
    __syncthreads();

    for (int it = 0; it < nk; ++it) {
        const int buf = it & 1;
        if (it + 1 < nk) {
            const int kk = gs.k0 + (it + 1) * 64;
#pragma unroll
            for (int i = 0; i < BM / 32; ++i) {
                int cid = t + i * 256, row = cid >> 3, c = cid & 7;
                g2l16(A + (size_t)(m0 + row) * Kd + kk + ((c ^ (row & 7)) << 3), &As[buf ^ 1][cid << 3]);
            }
#pragma unroll
            for (int i = 0; i < BN / 32; ++i) {
                int cid = t + i * 256, row = cid >> 3, c = cid & 7;
                g2l16(W + (size_t)(n0 + row) * Kd + kk + ((c ^ (row & 7)) << 3), &Bs[buf ^ 1][cid << 3]);
            }
        }
#pragma unroll
        for (int ks = 0; ks < 2; ++ks) {
            bf16x8 af[MF], bfr[NF];
#pragma unroll
            for (int m = 0; m < MF; ++m) {
                int row = wm * (MF * 16) + m * 16 + r16;
                af[m] = *(const bf16x8*)&As[buf][(row << 6) + (((ks * 4 + g) ^ (row & 7)) << 3)];
            }
#pragma unroll
            for (int n = 0; n < NF; ++n) {
                int row = wn * (NF * 16) + n * 16 + r16;
                bfr[n] = *(const bf16x8*)&Bs[buf][(row << 6) + (((ks * 4 + g) ^ (row & 7)) << 3)];
            }
#pragma unroll
            for (int m = 0; m < MF; ++m)
#pragma unroll
                for (int n = 0; n < NF; ++n)
                    acc[m][n] = mfma16(af[m], bfr[n], acc[m][n]);
        }
        __syncthreads();
    }
    const int epi = gs.epi;
#pragma unroll
    for (int m = 0; m < MF; ++m) {
        int row0 = m0 + wm * (MF * 16) + m * 16 + g * 4;
#pragma unroll
        for (int n = 0; n < NF; ++n) {
            int col = n0 + wn * (NF * 16) + n * 16 + r16;
            float bv = gs.bias ? gs.bias[col] : 0.f;
            float v[4];
#pragma unroll
            for (int r = 0; r < 4; ++r) v[r] = (acc[m][n][r] + bv) * gs.oscale;
            if (epi == 1) {
#pragma unroll
                for (int r = 0; r < 4; ++r) v[r] = fmaxf(v[r], 0.f);
            }
            if (epi == 3) {
                int bb = row0 >> 10, s = row0 & 1023;
                u16* o = (u16*)gs.out +
                         ((size_t)(bb * 8 + (col >> 6)) * 64 + (col & 63)) * 1024 + s;
                *(ushort4*)o = make_ushort4(f2bf(v[0]), f2bf(v[1]), f2bf(v[2]), f2bf(v[3]));
            } else {
                u16* o = (u16*)gs.out;
#pragma unroll
                for (int r = 0; r < 4; ++r) o[(size_t)(row0 + r) * N + col] = f2bf(v[r]);
            }
        }
    }
}

// ---------------------------------------------------------------- attention (partial over Lk/2)
// Scores pre-scaled by log2e (exp -> exp2). 64-key chunks; Ks/Vs source-XOR-
// swizzled; grid (h, b*2+p, qtile) so flat%8 = h (per-head XCD L2 locality).
__global__ __launch_bounds__(512, 4) void attn_part_kernel(
    const u16* __restrict__ Q, const u16* __restrict__ K,
    const u16* __restrict__ VT, const u32* __restrict__ mb,
    u16* __restrict__ OP, float2* __restrict__ ML) {
    constexpr int Lq = 1024, Lk = 1024, NCH = 8;
    constexpr float MFILL = 1.442695041e-9f;   // 1e-9 * log2e (bit-space)
    constexpr float DTHR  = 11.5415603f;       // 8 * log2e
    const int t = threadIdx.x, lane = t & 63, wave = t >> 6;
    const int g = lane >> 4, r16 = lane & 15;
    const int h = blockIdx.x;
    const int b = blockIdx.y >> 1, p = blockIdx.y & 1;
    const int bh = b * 8 + h;
    const int q0 = blockIdx.z * 128 + wave * 16;
    const int kc0 = p * (Lk >> 1);

    __shared__ __align__(16) u16 Ks[2][64][64];   // [k][d], source-swizzled
    __shared__ __align__(16) u16 Vs[2][64][64];   // [d][k], source-swizzled
    __shared__ __align__(16) u16 Pl[8][16][72];   // row stride 144B

    const size_t qrow = (size_t)b * Lq + q0 + r16;
    const u16* qp = Q + qrow * 512 + h * 64 + g * 8;
    bf16x8 qb0 = ldg8(qp), qb1 = ldg8(qp + 32);
    const u32* mrow = mb + qrow * (Lk >> 5);

    const int sid = t & 255;
    const bool isK = t < 256;
    const int s1 = sid, s2 = sid + 256;
    const int r1 = s1 >> 3, c1 = s1 & 7;
    const int r2 = s2 >> 3, c2 = s2 & 7;
    const u16 *sgA, *sgB;
    if (isK) {
        const u16* kbase = K + (size_t)b * Lk * 512 + h * 64;
        sgA = kbase + (size_t)(kc0 + r1) * 512 + ((c1 ^ (r1 & 7)) << 3);
        sgB = kbase + (size_t)(kc0 + r2) * 512 + ((c2 ^ (r2 & 7)) << 3);
    } else {
        const u16* vbase = VT + (size_t)bh * 64 * Lk + kc0;
        sgA = vbase + (size_t)r1 * Lk + ((c1 ^ (r1 & 7)) << 3);
        sgB = vbase + (size_t)r2 * Lk + ((c2 ^ (r2 & 7)) << 3);
    }
    const size_t adv = isK ? (size_t)64 * 512 : 64;
    u16* const base = isK ? &Ks[0][0][0] : &Vs[0][0][0];
    u16* const slA = base + s1 * 8;
    u16* const slB = base + s2 * 8;

    f32x4 acc[4];
#pragma unroll
    for (int dt = 0; dt < 4; ++dt) acc[dt] = f32x4{0.f, 0.f, 0.f, 0.f};
    float mrun = -INFINITY, lrun = 0.f;
    const f32x4 zf = {0.f, 0.f, 0.f, 0.f};

    g2l16(sgA, slA);
    g2l16(sgB, slB);
    __syncthreads();

#pragma unroll
    for (int c = 0; c < NCH; ++c) {
        const int buf = c & 1, nbuf = buf ^ 1;
        const int kc = kc0 + c * 64;
        if (c + 1 < NCH) {
            g2l16(sgA + (size_t)(c + 1) * adv, slA + nbuf * 4096);
            g2l16(sgB + (size_t)(c + 1) * adv, slB + nbuf * 4096);
        }
        const u16* kb = &Ks[buf][0][0];
        const u16* vb = &Vs[buf][0][0];
        f32x4 s[4];
#pragma unroll
        for (int j = 0; j < 4; ++j) {
            int row = j * 16 + r16;
            bf16x8 ka0 = *(const bf16x8*)(kb + row * 64 + ((g ^ (row & 7)) << 3));
            bf16x8 ka1 = *(const bf16x8*)(kb + row * 64 + (((4 + g) ^ (row & 7)) << 3));
            s[j] = mfma16(ka0, qb0, zf);
            s[j] = mfma16(ka1, qb1, s[j]);
        }
        u32 mw0 = mrow[kc >> 5], mw1 = mrow[(kc >> 5) + 1];
        float sv[16];
#pragma unroll
        for (int j = 0; j < 4; ++j) {
            u32 w = (j < 2) ? mw0 : mw1;
            int bbase = (16 * j) & 31;
#pragma unroll
            for (int r = 0; r < 4; ++r) {
                int bit = bbase + g * 4 + r;
                sv[4 * j + r] = ((w >> bit) & 1) ? s[j][r] : MFILL;
            }
        }
        float tm = fmaxf(fmaxf(fmaxf(sv[0], sv[1]), fmaxf(sv[2], sv[3])),
                         fmaxf(fmaxf(sv[4], sv[5]), fmaxf(sv[6], sv[7])));
        float tm2 = fmaxf(fmaxf(fmaxf(sv[8], sv[9]), fmaxf(sv[10], sv[11])),
                          fmaxf(fmaxf(sv[12], sv[13]), fmaxf(sv[14], sv[15])));
        tm = fmaxf(tm, tm2);
        tm = fmaxf(tm, __shfl_xor(tm, 16));
        tm = fmaxf(tm, __shfl_xor(tm, 32));
        if (!__all(tm <= mrun + DTHR)) {
            float mn = fmaxf(mrun, tm);
            float alpha = ex2(mrun - mn);
            mrun = mn;
            lrun *= alpha;
#pragma unroll
            for (int r = 0; r < 4; ++r) {
                float ar = __shfl(alpha, g * 4 + r);
#pragma unroll
                for (int dt = 0; dt < 4; ++dt) acc[dt][r] *= ar;
            }
        }
        float ts = 0.f;
#pragma unroll
        for (int j = 0; j < 16; ++j) { sv[j] = ex2(sv[j] - mrun); ts += sv[j]; }
        ts += __shfl_xor(ts, 16);
        ts += __shfl_xor(ts, 32);
        lrun += ts;

#pragma unroll
        for (int j = 0; j < 4; ++j) {
            uint2 u;
            u.x = pk2(sv[4 * j], sv[4 * j + 1]);
            u.y = pk2(sv[4 * j + 2], sv[4 * j + 3]);
            *(uint2*)&Pl[wave][r16][16 * j + g * 4] = u;
        }
        bf16x8 pf0 = *(const bf16x8*)&Pl[wave][r16][g * 8];
        bf16x8 pf1 = *(const bf16x8*)&Pl[wave][r16][32 + g * 8];
#pragma unroll
        for (int dt = 0; dt < 4; ++dt) {
            int row = dt * 16 + r16;
            bf16x8 vf0 = *(const bf16x8*)(vb + row * 64 + ((g ^ (row & 7)) << 3));
            bf16x8 vf1 = *(const bf16x8*)(vb + row * 64 + (((4 + g) ^ (row & 7)) << 3));
            acc[dt] = mfma16(pf0, vf0, acc[dt]);
            acc[dt] = mfma16(pf1, vf1, acc[dt]);
        }
        __syncthreads();
    }

    if (lane < 16)
        ML[(size_t)p * 32768 + (size_t)bh * 1024 + q0 + lane] = make_float2(mrun, lrun);
    const size_t obase = (size_t)p * 2097152 + ((size_t)bh * 1024 + q0) * 64;
#pragma unroll
    for (int dt = 0; dt < 4; ++dt)
#pragma unroll
        for (int r = 0; r < 4; ++r)
            OP[obase + (size_t)(g * 4 + r) * 64 + dt * 16 + r16] = f2bf(acc[dt][r]);
}

// ---------------------------------------------------------------- attention combine (2 partials, 8 elems/thread)
__global__ __launch_bounds__(256) void attn_combine_kernel(
    const u16* __restrict__ OP, const float2* __restrict__ ML, u16* __restrict__ O) {
    int gid = blockIdx.x * 256 + threadIdx.x;
    int row = gid >> 3, seg = gid & 7;
    size_t idx = (size_t)row * 64 + seg * 8;
    float2 ml0 = ML[row], ml1 = ML[32768 + row];
    float M = fmaxf(ml0.x, ml1.x);
    float w0 = ex2(ml0.x - M), w1 = ex2(ml1.x - M);
    float rden = 1.f / (ml0.y * w0 + ml1.y * w1);
    w0 *= rden; w1 *= rden;
    float a[8], b[8];
    unp8(*(const uint4*)(OP + idx), a);
    unp8(*(const uint4*)(OP + 2097152 + idx), b);
    int bh = row >> 10, q = row & 1023;
    int bb = bh >> 3, h = bh & 7;
    u16* o = O + ((size_t)(bb * 1024 + q)) * 512 + h * 64 + seg * 8;
    uint4 r;
    r.x = pk2(a[0] * w0 + b[0] * w1, a[1] * w0 + b[1] * w1);
    r.y = pk2(a[2] * w0 + b[2] * w1, a[3] * w0 + b[3] * w1);
    r.z = pk2(a[4] * w0 + b[4] * w1, a[5] * w0 + b[5] * w1);
    r.w = pk2(a[6] * w0 + b[6] * w1, a[7] * w0 + b[7] * w1);
    *(uint4*)o = r;
}

// ---------------------------------------------------------------- LayerNorm (bf16 in/out)
// x = a + b1 + b2 (all bf16) ; y = LN(x)*g + b
// MODE 0: yb + qb(=bf16(y+pos)) ; MODE 1: yb ; MODE 2: yf (f32)
template <int MODE>
__global__ __launch_bounds__(256) void ln_kernel(
    const u16* __restrict__ a, const u16* __restrict__ b1, const u16* __restrict__ b2,
    const float* __restrict__ gam, const float* __restrict__ bet,
    const u16* __restrict__ pos,
    u16* __restrict__ yb, u16* __restrict__ qb, float* __restrict__ yf) {
    const int lane = threadIdx.x & 63;
    const int row = blockIdx.x * 4 + (threadIdx.x >> 6);
    const size_t base = (size_t)row * 512 + lane * 8;
    float av[8], bv[8], cv[8];
    unp8(*(const uint4*)(a + base), av);
    unp8(*(const uint4*)(b1 + base), bv);
    unp8(*(const uint4*)(b2 + base), cv);
    float x[8];
#pragma unroll
    for (int j = 0; j < 8; ++j) x[j] = av[j] + bv[j] + cv[j];
    float s1 = 0.f, s2 = 0.f;
#pragma unroll
    for (int j = 0; j < 8; ++j) { s1 += x[j]; s2 += x[j] * x[j]; }
#pragma unroll
    for (int d = 1; d < 64; d <<= 1) { s1 += __shfl_xor(s1, d); s2 += __shfl_xor(s2, d); }
    float mean = s1 * (1.f / 512.f);
    float var = s2 * (1.f / 512.f) - mean * mean;
    float rs = rsqrtf(var + 1e-5f);
    float4 gv0 = ((const float4*)(gam + lane * 8))[0];
    float4 gv1 = ((const float4*)(gam + lane * 8))[1];
    float4 be0 = ((const float4*)(bet + lane * 8))[0];
    float4 be1 = ((const float4*)(bet + lane * 8))[1];
    float gg[8] = {gv0.x, gv0.y, gv0.z, gv0.w, gv1.x, gv1.y, gv1.z, gv1.w};
    float bb[8] = {be0.x, be0.y, be0.z, be0.w, be1.x, be1.y, be1.z, be1.w};
    float y[8];
#pragma unroll
    for (int j = 0; j < 8; ++j) y[j] = (x[j] - mean) * rs * gg[j] + bb[j];
    if (MODE == 2) {
        ((float4*)(yf + base))[0] = make_float4(y[0], y[1], y[2], y[3]);
        ((float4*)(yf + base))[1] = make_float4(y[4], y[5], y[6], y[7]);
        return;
    }
    uint4 r;
    r.x = pk2(y[0], y[1]); r.y = pk2(y[2], y[3]);
    r.z = pk2(y[4], y[5]); r.w = pk2(y[6], y[7]);
    *(uint4*)(yb + base) = r;
    if (MODE == 0) {
        float pv[8];
        unp8(*(const uint4*)(pos + base), pv);
        uint4 q;
        q.x = pk2(y[0] + pv[0], y[1] + pv[1]);
        q.y = pk2(y[2] + pv[2], y[3] + pv[3]);
        q.z = pk2(y[4] + pv[4], y[5] + pv[5]);
        q.w = pk2(y[6] + pv[6], y[7] + pv[7]);
        *(uint4*)(qb + base) = q;
    }
}

// ---------------------------------------------------------------- host
extern "C" void kernel_launch(void* const* d_in, const int* in_sizes, int n_in,
                              void* d_out, int out_size, void* d_ws, size_t ws_size,
                              hipStream_t stream) {
    (void)in_sizes; (void)n_in; (void)out_size; (void)ws_size;
    const float* tgt      = (const float*)d_in[0];
    const float* memory   = (const float*)d_in[1];
    const float* tgt_pos  = (const float*)d_in[2];
    const float* mem_pos  = (const float*)d_in[3];
    const int*   tgt_mask = (const int*)d_in[4];
    const int*   mem_mask = (const int*)d_in[5];
    const float* sa_b[4] = {(const float*)d_in[7], (const float*)d_in[9],
                            (const float*)d_in[11], (const float*)d_in[13]};
    const float* ca_b[4] = {(const float*)d_in[15], (const float*)d_in[17],
                            (const float*)d_in[19], (const float*)d_in[21]};
    const float* ln1_g = (const float*)d_in[22]; const float* ln1_b = (const float*)d_in[23];
    const float* ln2_g = (const float*)d_in[24]; const float* ln2_b = (const float*)d_in[25];
    const float* ln3_g = (const float*)d_in[26]; const float* ln3_b = (const float*)d_in[27];
    const float* mlp_b1 = (const float*)d_in[29];
    const float* mlp_b2 = (const float*)d_in[31];

    const size_t MiB = 1024 * 1024;
    char* ws = (char*)d_ws;           // ws_size = 256 MiB
    u16*  WT  = (u16*)(ws + 0);
    u32*  MBS = (u32*)(ws + 8 * MiB);
    u32*  MBC = (u32*)(ws + 8 * MiB + 512 * 1024);
    u16*  QIN = (u16*)(ws + 9 * MiB);
    u16*  TGTB= (u16*)(ws + 13 * MiB);
    u16*  MEMB= (u16*)(ws + 17 * MiB);
    u16*  MKB = (u16*)(ws + 21 * MiB);
    u16*  QM  = (u16*)(ws + 25 * MiB);
    u16*  KMS = (u16*)(ws + 29 * MiB);
    u16*  KMC = (u16*)(ws + 33 * MiB);
    u16*  VTS = (u16*)(ws + 37 * MiB);
    u16*  VTC = (u16*)(ws + 41 * MiB);
    u16*  ATNB= (u16*)(ws + 45 * MiB);
    u16*  P1B = (u16*)(ws + 49 * MiB);     // 4 MiB bf16 GEMM partial 1
    u16*  X1B = (u16*)(ws + 53 * MiB);     // 4 MiB bf16 residual
    u16*  MQB = (u16*)(ws + 57 * MiB);     // 4 MiB
    u16*  X2B = (u16*)(ws + 61 * MiB);     // 4 MiB bf16 residual + FFN input
    u16*  TPB = (u16*)(ws + 65 * MiB);     // 4 MiB bf16 tgt_pos
    u16*  P2B = (u16*)(ws + 69 * MiB);     // 4 MiB bf16 GEMM partial 2
    u16*  FFH = (u16*)(ws + 9 * MiB);      // 16 MiB, aliases QIN..MKB (dead by FFN)
    u16*  OPB = (u16*)(ws + 96 * MiB);     // 2 x 4 MiB bf16 attn partials
    float2* MLB = (float2*)(ws + 120 * MiB); // 512 KiB m,l

    u16* wt[10];
    for (int z = 0; z < 8; ++z) wt[z] = WT + (size_t)z * 262144;
    wt[8] = WT + 2097152;
    wt[9] = WT + 3145728;

    ProArgs pa;
    pa.w[0] = (const float*)d_in[6];  pa.w[1] = (const float*)d_in[8];
    pa.w[2] = (const float*)d_in[10]; pa.w[3] = (const float*)d_in[12];
    pa.w[4] = (const float*)d_in[14]; pa.w[5] = (const float*)d_in[16];
    pa.w[6] = (const float*)d_in[18]; pa.w[7] = (const float*)d_in[20];
    pa.w[8] = (const float*)d_in[28]; pa.w[9] = (const float*)d_in[30];
    pa.wtbase = WT;
    pa.tgt = (const float4*)tgt; pa.tpos = (const float4*)tgt_pos;
    pa.mem = (const float4*)memory; pa.mpos = (const float4*)mem_pos;
    pa.qin = (ushort4*)QIN; pa.tgtb = (ushort4*)TGTB;
    pa.memb = (ushort4*)MEMB; pa.mkb = (ushort4*)MKB;
    pa.tposb = (ushort4*)TPB;
    pa.m1 = (const int4*)tgt_mask; pa.m2 = (const int4*)mem_mask;
    pa.o1 = MBS; pa.o2 = MBC;
    prologue_kernel<<<16384, 256, 0, stream>>>(pa);

    const float QSC = 0.125f * 1.44269504f;   // fold log2e into Q (exp2 softmax)
    GemmArgs5 ga;
    // Batched: SA Q,K,V + CA K,V
    ga.s[0] = {QIN,  wt[0], sa_b[0], QM,  QSC, 0, 0, 512};
    ga.s[1] = {QIN,  wt[1], sa_b[1], KMS, 1.f, 0, 0, 512};
    ga.s[2] = {TGTB, wt[2], sa_b[2], VTS, 1.f, 3, 0, 512};
    ga.s[3] = {MKB,  wt[5], ca_b[1], KMC, 1.f, 0, 0, 512};
    ga.s[4] = {MEMB, wt[6], ca_b[2], VTC, 1.f, 3, 0, 512};
    gemm_kernel<128, 64><<<dim3(8, 32, 5), 256, 0, stream>>>(ga, 4096, 512, 512);
    attn_part_kernel<<<dim3(8, 8, 8), 512, 0, stream>>>(QM, KMS, VTS, MBS, OPB, MLB);
    attn_combine_kernel<<<1024, 256, 0, stream>>>(OPB, MLB, ATNB);
    // SA O-proj, K-split x2 -> P1,P2
    ga.s[0] = {ATNB, wt[3], sa_b[3], P1B, 1.f, 0, 0,   256};
    ga.s[1] = {ATNB, wt[3], nullptr, P2B, 1.f, 0, 256, 256};
    ga.s[2] = ga.s[0]; ga.s[3] = ga.s[0]; ga.s[4] = ga.s[0];
    gemm_kernel<64, 64><<<dim3(8, 64, 2), 256, 0, stream>>>(ga, 4096, 512, 512);
    ln_kernel<0><<<1024, 256, 0, stream>>>(TGTB, P1B, P2B, ln1_g, ln1_b, TPB, X1B, MQB, nullptr);

    // CA Q projection
    ga.s[0] = {MQB, wt[4], ca_b[0], QM, QSC, 0, 0, 512};
    ga.s[1] = ga.s[0]; ga.s[2] = ga.s[0]; ga.s[3] = ga.s[0]; ga.s[4] = ga.s[0];
    gemm_kernel<64, 64><<<dim3(8, 64, 1), 256, 0, stream>>>(ga, 4096, 512, 512);
    attn_part_kernel<<<dim3(8, 8, 8), 512, 0, stream>>>(QM, KMC, VTC, MBC, OPB, MLB);
    attn_combine_kernel<<<1024, 256, 0, stream>>>(OPB, MLB, ATNB);
    // CA O-proj, K-split x2
    ga.s[0] = {ATNB, wt[7], ca_b[3], P1B, 1.f, 0, 0,   256};
    ga.s[1] = {ATNB, wt[7], nullptr, P2B, 1.f, 0, 256, 256};
    ga.s[2] = ga.s[0]; ga.s[3] = ga.s[0]; ga.s[4] = ga.s[0];
    gemm_kernel<64, 64><<<dim3(8, 64, 2), 256, 0, stream>>>(ga, 4096, 512, 512);
    ln_kernel<1><<<1024, 256, 0, stream>>>(X1B, P1B, P2B, ln2_g, ln2_b, nullptr, X2B, nullptr, nullptr);

    // FFN1 (relu)
    ga.s[0] = {X2B, wt[8], mlp_b1, FFH, 1.f, 1, 0, 512};
    ga.s[1] = ga.s[0]; ga.s[2] = ga.s[0]; ga.s[3] = ga.s[0]; ga.s[4] = ga.s[0];
    gemm_kernel<128, 64><<<dim3(32, 32, 1), 256, 0, stream>>>(ga, 4096, 2048, 512);
    // FFN2, K-split x2 (K=2048)
    ga.s[0] = {FFH, wt[9], mlp_b2, P1B, 1.f, 0, 0,    1024};
    ga.s[1] = {FFH, wt[9], nullptr, P2B, 1.f, 0, 1024, 1024};
    ga.s[2] = ga.s[0]; ga.s[3] = ga.s[0]; ga.s[4] = ga.s[0];
    gemm_kernel<64, 64><<<dim3(8, 64, 2), 256, 0, stream>>>(ga, 4096, 512, 2048);
    ln_kernel<2><<<1024, 256, 0, stream>>>(X2B, P1B, P2B, ln3_g, ln3_b, nullptr,
                                           nullptr, nullptr, (float*)d_out);
}

// Round 19
// 158.277 us; speedup vs baseline: 1.0685x; 1.0685x over previous
//
#include <hip/hip_runtime.h>
#include <stdint.h>

typedef unsigned int u32;
typedef unsigned long long u64;
typedef unsigned short u16;
typedef __attribute__((ext_vector_type(8))) __bf16 bf16x8;
typedef __attribute__((ext_vector_type(4))) float f32x4;

#define DEV __device__ __forceinline__

DEV u16 f2bf(float f) {
    u32 x = __builtin_bit_cast(u32, f);
    u32 r = (x + 0x7FFFu + ((x >> 16) & 1u)) >> 16;
    return (u16)r;
}

DEV float bf2f(u16 x) {
    u32 u = (u32)x << 16;
    return __builtin_bit_cast(float, u);
}

DEV void unp8(uint4 u, float* f) {
    f[0] = bf2f((u16)u.x); f[1] = bf2f((u16)(u.x >> 16));
    f[2] = bf2f((u16)u.y); f[3] = bf2f((u16)(u.y >> 16));
    f[4] = bf2f((u16)u.z); f[5] = bf2f((u16)(u.z >> 16));
    f[6] = bf2f((u16)u.w); f[7] = bf2f((u16)(u.w >> 16));
}

DEV bf16x8 ldg8(const u16* p) {
    return __builtin_bit_cast(bf16x8, *(const uint4*)p);
}

DEV u32 pk2(float a, float b) {
    return (u32)f2bf(a) | ((u32)f2bf(b) << 16);
}

DEV float ex2(float x) {
    return __builtin_amdgcn_exp2f(x);
}

DEV void g2l16(const u16* g, u16* l) {
    __builtin_amdgcn_global_load_lds(
        (const __attribute__((address_space(1))) u32*)g,
        (__attribute__((address_space(3))) u32*)l, 16, 0, 0);
}

DEV f32x4 mfma16(bf16x8 a, bf16x8 b, f32x4 c) {
    return __builtin_amdgcn_mfma_f32_16x16x32_bf16(a, b, c, 0, 0, 0);
}

// ---------------------------------------------------------------- prologue
// sections: [0,10240) wtrans ; [10240,12288) prep ; [12288,16384) packmask
struct ProArgs {
    const float* w[10];
    u16* wtbase;
    const float4 *tgt, *tpos, *mem, *mpos;
    ushort4 *qin, *tgtb, *memb, *mkb, *tposb;
    const int4 *m1, *m2;
    u32 *o1, *o2;
};
__global__ __launch_bounds__(256) void prologue_kernel(ProArgs a) {
    const int bx = blockIdx.x, t = threadIdx.x;
    if (bx < 10240) {
        int z = bx >> 10, bxx = bx & 1023;
        int Kd = (z == 9) ? 2048 : 512;
        int Nd = (z == 8) ? 2048 : 512;
        size_t off = (z < 8) ? (size_t)z * 262144
                             : (z == 8 ? (size_t)2097152 : (size_t)3145728);
        u16* out = a.wtbase + off;
        int nx = Nd / 32;
        int txile = bxx % nx, tyile = bxx / nx;
        if (tyile >= Kd / 32) return;
        const float* w = a.w[z];
        __shared__ float tl[32][33];
        int tx = t & 31, ty = t >> 5;
#pragma unroll
        for (int j = 0; j < 4; ++j)
            tl[ty + j * 8][tx] = w[(size_t)(tyile * 32 + ty + j * 8) * Nd + txile * 32 + tx];
        __syncthreads();
#pragma unroll
        for (int j = 0; j < 4; ++j)
            out[(size_t)(txile * 32 + ty + j * 8) * Kd + tyile * 32 + tx] = f2bf(tl[tx][ty + j * 8]);
    } else if (bx < 12288) {
        int i = (bx - 10240) * 256 + t;
        float4 tt = a.tgt[i], p = a.tpos[i], m = a.mem[i], mp = a.mpos[i];
        a.qin[i]  = make_ushort4(f2bf(tt.x + p.x), f2bf(tt.y + p.y), f2bf(tt.z + p.z), f2bf(tt.w + p.w));
        a.tgtb[i] = make_ushort4(f2bf(tt.x), f2bf(tt.y), f2bf(tt.z), f2bf(tt.w));
        a.memb[i] = make_ushort4(f2bf(m.x), f2bf(m.y), f2bf(m.z), f2bf(m.w));
        a.mkb[i]  = make_ushort4(f2bf(m.x + mp.x), f2bf(m.y + mp.y), f2bf(m.z + mp.z), f2bf(m.w + mp.w));
        a.tposb[i]= make_ushort4(f2bf(p.x), f2bf(p.y), f2bf(p.z), f2bf(p.w));
    } else {
        int i = (bx - 12288) * 256 + t;
        const int n8 = 524288;
        bool first = i < n8;
        int idx = first ? i : i - n8;
        const int4* src = first ? a.m1 : a.m2;
        int4 x = src[idx * 2], y = src[idx * 2 + 1];
        u32 by = (u32)(x.x != 0) | ((u32)(x.y != 0) << 1) | ((u32)(x.z != 0) << 2) |
                 ((u32)(x.w != 0) << 3) | ((u32)(y.x != 0) << 4) | ((u32)(y.y != 0) << 5) |
                 ((u32)(y.z != 0) << 6) | ((u32)(y.w != 0) << 7);
        u32 w = by | (__shfl_down(by, 1) << 8) | (__shfl_down(by, 2) << 16) |
                (__shfl_down(by, 3) << 24);
        if ((t & 3) == 0) (first ? a.o1 : a.o2)[idx >> 2] = w;
    }
}

// ---------------------------------------------------------------- GEMM
// C[M][N] = (A[M][k0:k0+klen] @ W^T[N][k0:k0+klen] + bias?) * oscale -> bf16
// epi: 0 bf16, 1 bf16+relu, 3 bf16 V-transposed -> VT[b*8+h][d][s] (S=1024)
struct GemmSet {
    const u16* A; const u16* W; const float* bias; void* out;
    float oscale; int epi; int k0; int klen;
};
struct GemmArgs5 { GemmSet s[5]; };

template <int BM, int BN>
__global__ __launch_bounds__(256) void gemm_kernel(GemmArgs5 args, int M, int N, int Kd) {
    constexpr int MF = BM / 32, NF = BN / 32;
    const GemmSet gs = args.s[blockIdx.z];
    const u16* __restrict__ A = gs.A;
    const u16* __restrict__ W = gs.W;
    const int t = threadIdx.x;
    const int lane = t & 63;
    const int g = lane >> 4, r16 = lane & 15;
    const int wave = t >> 6;
    const int wm = wave >> 1, wn = wave & 1;
    const int nwg = gridDim.x * gridDim.y;
    const int fid = blockIdx.y * gridDim.x + blockIdx.x;
    const int qq = nwg >> 3;
    const int lid = (fid & 7) * qq + (fid >> 3);
    const int m0 = (lid / gridDim.x) * BM, n0 = (lid % gridDim.x) * BN;

    __shared__ __align__(16) u16 As[BM * 64];
    __shared__ __align__(16) u16 Bs[BN * 64];

    f32x4 acc[MF][NF];
#pragma unroll
    for (int m = 0; m < MF; ++m)
#pragma unroll
        for (int n = 0; n < NF; ++n) acc[m][n] = f32x4{0.f, 0.f, 0.f, 0.f};

    const int kend = gs.k0 + gs.klen;
    for (int kk = gs.k0; kk < kend; kk += 64) {
        __syncthreads();
#pragma unroll
        for (int i = 0; i < BM / 32; ++i) {
            int cid = t + i * 256, row = cid >> 3, c = cid & 7;
            g2l16(A + (size_t)(m0 + row) * Kd + kk + ((c ^ (row & 7)) << 3), &As[cid << 3]);
        }
#pragma unroll
        for (int i = 0; i < BN / 32; ++i) {
            int cid = t + i * 256, row = cid >> 3, c = cid & 7;
            g2l16(W + (size_t)(n0 + row) * Kd + kk + ((c ^ (row & 7)) << 3), &Bs[cid << 3]);
        }
        __syncthreads();
#pragma unroll
        for (int ks = 0; ks < 2; ++ks) {
            bf16x8 af[MF], bfr[NF];
#pragma unroll
            for (int m = 0; m < MF; ++m) {
                int row = wm * (MF * 16) + m * 16 + r16;
                af[m] = *(const bf16x8*)&As[(row << 6) + (((ks * 4 + g) ^ (row & 7)) << 3)];
            }
#pragma unroll
            for (int n = 0; n < NF; ++n) {
                int row = wn * (NF * 16) + n * 16 + r16;
                bfr[n] = *(const bf16x8*)&Bs[(row << 6) + (((ks * 4 + g) ^ (row & 7)) << 3)];
            }
#pragma unroll
            for (int m = 0; m < MF; ++m)
#pragma unroll
                for (int n = 0; n < NF; ++n)
                    acc[m][n] = mfma16(af[m], bfr[n], acc[m][n]);
        }
    }
    const int epi = gs.epi;
#pragma unroll
    for (int m = 0; m < MF; ++m) {
        int row0 = m0 + wm * (MF * 16) + m * 16 + g * 4;
#pragma unroll
        for (int n = 0; n < NF; ++n) {
            int col = n0 + wn * (NF * 16) + n * 16 + r16;
            float bv = gs.bias ? gs.bias[col] : 0.f;
            float v[4];
#pragma unroll
            for (int r = 0; r < 4; ++r) v[r] = (acc[m][n][r] + bv) * gs.oscale;
            if (epi == 1) {
#pragma unroll
                for (int r = 0; r < 4; ++r) v[r] = fmaxf(v[r], 0.f);
            }
            if (epi == 3) {
                int bb = row0 >> 10, s = row0 & 1023;
                u16* o = (u16*)gs.out +
                         ((size_t)(bb * 8 + (col >> 6)) * 64 + (col & 63)) * 1024 + s;
                *(ushort4*)o = make_ushort4(f2bf(v[0]), f2bf(v[1]), f2bf(v[2]), f2bf(v[3]));
            } else {
                u16* o = (u16*)gs.out;
#pragma unroll
                for (int r = 0; r < 4; ++r) o[(size_t)(row0 + r) * N + col] = f2bf(v[r]);
            }
        }
    }
}

// ---------------------------------------------------------------- attention (partial over Lk/2)
// Scores pre-scaled by log2e (exp -> exp2). 64-key chunks; Ks/Vs source-XOR-
// swizzled; grid (h, b*2+p, qtile) so flat%8 = h (per-head XCD L2 locality).
__global__ __launch_bounds__(512, 4) void attn_part_kernel(
    const u16* __restrict__ Q, const u16* __restrict__ K,
    const u16* __restrict__ VT, const u32* __restrict__ mb,
    u16* __restrict__ OP, float2* __restrict__ ML) {
    constexpr int Lq = 1024, Lk = 1024, NCH = 8;
    constexpr float MFILL = 1.442695041e-9f;   // 1e-9 * log2e (bit-space)
    constexpr float DTHR  = 11.5415603f;       // 8 * log2e
    const int t = threadIdx.x, lane = t & 63, wave = t >> 6;
    const int g = lane >> 4, r16 = lane & 15;
    const int h = blockIdx.x;
    const int b = blockIdx.y >> 1, p = blockIdx.y & 1;
    const int bh = b * 8 + h;
    const int q0 = blockIdx.z * 128 + wave * 16;
    const int kc0 = p * (Lk >> 1);

    __shared__ __align__(16) u16 Ks[2][64][64];   // [k][d], source-swizzled
    __shared__ __align__(16) u16 Vs[2][64][64];   // [d][k], source-swizzled
    __shared__ __align__(16) u16 Pl[8][16][72];   // row stride 144B

    const size_t qrow = (size_t)b * Lq + q0 + r16;
    const u16* qp = Q + qrow * 512 + h * 64 + g * 8;
    bf16x8 qb0 = ldg8(qp), qb1 = ldg8(qp + 32);
    const u32* mrow = mb + qrow * (Lk >> 5);

    const int sid = t & 255;
    const bool isK = t < 256;
    const int s1 = sid, s2 = sid + 256;
    const int r1 = s1 >> 3, c1 = s1 & 7;
    const int r2 = s2 >> 3, c2 = s2 & 7;
    const u16 *sgA, *sgB;
    if (isK) {
        const u16* kbase = K + (size_t)b * Lk * 512 + h * 64;
        sgA = kbase + (size_t)(kc0 + r1) * 512 + ((c1 ^ (r1 & 7)) << 3);
        sgB = kbase + (size_t)(kc0 + r2) * 512 + ((c2 ^ (r2 & 7)) << 3);
    } else {
        const u16* vbase = VT + (size_t)bh * 64 * Lk + kc0;
        sgA = vbase + (size_t)r1 * Lk + ((c1 ^ (r1 & 7)) << 3);
        sgB = vbase + (size_t)r2 * Lk + ((c2 ^ (r2 & 7)) << 3);
    }
    const size_t adv = isK ? (size_t)64 * 512 : 64;
    u16* const base = isK ? &Ks[0][0][0] : &Vs[0][0][0];
    u16* const slA = base + s1 * 8;
    u16* const slB = base + s2 * 8;

    f32x4 acc[4];
#pragma unroll
    for (int dt = 0; dt < 4; ++dt) acc[dt] = f32x4{0.f, 0.f, 0.f, 0.f};
    float mrun = -INFINITY, lrun = 0.f;
    const f32x4 zf = {0.f, 0.f, 0.f, 0.f};

    g2l16(sgA, slA);
    g2l16(sgB, slB);
    __syncthreads();

#pragma unroll
    for (int c = 0; c < NCH; ++c) {
        const int buf = c & 1, nbuf = buf ^ 1;
        const int kc = kc0 + c * 64;
        if (c + 1 < NCH) {
            g2l16(sgA + (size_t)(c + 1) * adv, slA + nbuf * 4096);
            g2l16(sgB + (size_t)(c + 1) * adv, slB + nbuf * 4096);
        }
        const u16* kb = &Ks[buf][0][0];
        const u16* vb = &Vs[buf][0][0];
        f32x4 s[4];
#pragma unroll
        for (int j = 0; j < 4; ++j) {
            int row = j * 16 + r16;
            bf16x8 ka0 = *(const bf16x8*)(kb + row * 64 + ((g ^ (row & 7)) << 3));
            bf16x8 ka1 = *(const bf16x8*)(kb + row * 64 + (((4 + g) ^ (row & 7)) << 3));
            s[j] = mfma16(ka0, qb0, zf);
            s[j] = mfma16(ka1, qb1, s[j]);
        }
        u32 mw0 = mrow[kc >> 5], mw1 = mrow[(kc >> 5) + 1];
        float sv[16];
#pragma unroll
        for (int j = 0; j < 4; ++j) {
            u32 w = (j < 2) ? mw0 : mw1;
            int bbase = (16 * j) & 31;
#pragma unroll
            for (int r = 0; r < 4; ++r) {
                int bit = bbase + g * 4 + r;
                sv[4 * j + r] = ((w >> bit) & 1) ? s[j][r] : MFILL;
            }
        }
        float tm = fmaxf(fmaxf(fmaxf(sv[0], sv[1]), fmaxf(sv[2], sv[3])),
                         fmaxf(fmaxf(sv[4], sv[5]), fmaxf(sv[6], sv[7])));
        float tm2 = fmaxf(fmaxf(fmaxf(sv[8], sv[9]), fmaxf(sv[10], sv[11])),
                          fmaxf(fmaxf(sv[12], sv[13]), fmaxf(sv[14], sv[15])));
        tm = fmaxf(tm, tm2);
        tm = fmaxf(tm, __shfl_xor(tm, 16));
        tm = fmaxf(tm, __shfl_xor(tm, 32));
        if (!__all(tm <= mrun + DTHR)) {
            float mn = fmaxf(mrun, tm);
            float alpha = ex2(mrun - mn);
            mrun = mn;
            lrun *= alpha;
#pragma unroll
            for (int r = 0; r < 4; ++r) {
                float ar = __shfl(alpha, g * 4 + r);
#pragma unroll
                for (int dt = 0; dt < 4; ++dt) acc[dt][r] *= ar;
            }
        }
        float ts = 0.f;
#pragma unroll
        for (int j = 0; j < 16; ++j) { sv[j] = ex2(sv[j] - mrun); ts += sv[j]; }
        ts += __shfl_xor(ts, 16);
        ts += __shfl_xor(ts, 32);
        lrun += ts;

#pragma unroll
        for (int j = 0; j < 4; ++j) {
            uint2 u;
            u.x = pk2(sv[4 * j], sv[4 * j + 1]);
            u.y = pk2(sv[4 * j + 2], sv[4 * j + 3]);
            *(uint2*)&Pl[wave][r16][16 * j + g * 4] = u;
        }
        bf16x8 pf0 = *(const bf16x8*)&Pl[wave][r16][g * 8];
        bf16x8 pf1 = *(const bf16x8*)&Pl[wave][r16][32 + g * 8];
#pragma unroll
        for (int dt = 0; dt < 4; ++dt) {
            int row = dt * 16 + r16;
            bf16x8 vf0 = *(const bf16x8*)(vb + row * 64 + ((g ^ (row & 7)) << 3));
            bf16x8 vf1 = *(const bf16x8*)(vb + row * 64 + (((4 + g) ^ (row & 7)) << 3));
            acc[dt] = mfma16(pf0, vf0, acc[dt]);
            acc[dt] = mfma16(pf1, vf1, acc[dt]);
        }
        __syncthreads();
    }

    if (lane < 16)
        ML[(size_t)p * 32768 + (size_t)bh * 1024 + q0 + lane] = make_float2(mrun, lrun);
    const size_t obase = (size_t)p * 2097152 + ((size_t)bh * 1024 + q0) * 64;
#pragma unroll
    for (int dt = 0; dt < 4; ++dt)
#pragma unroll
        for (int r = 0; r < 4; ++r)
            OP[obase + (size_t)(g * 4 + r) * 64 + dt * 16 + r16] = f2bf(acc[dt][r]);
}

// ---------------------------------------------------------------- attention combine (2 partials, 8 elems/thread)
__global__ __launch_bounds__(256) void attn_combine_kernel(
    const u16* __restrict__ OP, const float2* __restrict__ ML, u16* __restrict__ O) {
    int gid = blockIdx.x * 256 + threadIdx.x;
    int row = gid >> 3, seg = gid & 7;
    size_t idx = (size_t)row * 64 + seg * 8;
    float2 ml0 = ML[row], ml1 = ML[32768 + row];
    float M = fmaxf(ml0.x, ml1.x);
    float w0 = ex2(ml0.x - M), w1 = ex2(ml1.x - M);
    float rden = 1.f / (ml0.y * w0 + ml1.y * w1);
    w0 *= rden; w1 *= rden;
    float a[8], b[8];
    unp8(*(const uint4*)(OP + idx), a);
    unp8(*(const uint4*)(OP + 2097152 + idx), b);
    int bh = row >> 10, q = row & 1023;
    int bb = bh >> 3, h = bh & 7;
    u16* o = O + ((size_t)(bb * 1024 + q)) * 512 + h * 64 + seg * 8;
    uint4 r;
    r.x = pk2(a[0] * w0 + b[0] * w1, a[1] * w0 + b[1] * w1);
    r.y = pk2(a[2] * w0 + b[2] * w1, a[3] * w0 + b[3] * w1);
    r.z = pk2(a[4] * w0 + b[4] * w1, a[5] * w0 + b[5] * w1);
    r.w = pk2(a[6] * w0 + b[6] * w1, a[7] * w0 + b[7] * w1);
    *(uint4*)o = r;
}

// ---------------------------------------------------------------- LayerNorm (bf16 in/out)
// x = a + b1 + b2 (all bf16) ; y = LN(x)*g + b
// MODE 0: yb + qb(=bf16(y+pos)) ; MODE 1: yb ; MODE 2: yf (f32)
template <int MODE>
__global__ __launch_bounds__(256) void ln_kernel(
    const u16* __restrict__ a, const u16* __restrict__ b1, const u16* __restrict__ b2,
    const float* __restrict__ gam, const float* __restrict__ bet,
    const u16* __restrict__ pos,
    u16* __restrict__ yb, u16* __restrict__ qb, float* __restrict__ yf) {
    const int lane = threadIdx.x & 63;
    const int row = blockIdx.x * 4 + (threadIdx.x >> 6);
    const size_t base = (size_t)row * 512 + lane * 8;
    float av[8], bv[8], cv[8];
    unp8(*(const uint4*)(a + base), av);
    unp8(*(const uint4*)(b1 + base), bv);
    unp8(*(const uint4*)(b2 + base), cv);
    float x[8];
#pragma unroll
    for (int j = 0; j < 8; ++j) x[j] = av[j] + bv[j] + cv[j];
    float s1 = 0.f, s2 = 0.f;
#pragma unroll
    for (int j = 0; j < 8; ++j) { s1 += x[j]; s2 += x[j] * x[j]; }
#pragma unroll
    for (int d = 1; d < 64; d <<= 1) { s1 += __shfl_xor(s1, d); s2 += __shfl_xor(s2, d); }
    float mean = s1 * (1.f / 512.f);
    float var = s2 * (1.f / 512.f) - mean * mean;
    float rs = rsqrtf(var + 1e-5f);
    float4 gv0 = ((const float4*)(gam + lane * 8))[0];
    float4 gv1 = ((const float4*)(gam + lane * 8))[1];
    float4 be0 = ((const float4*)(bet + lane * 8))[0];
    float4 be1 = ((const float4*)(bet + lane * 8))[1];
    float gg[8] = {gv0.x, gv0.y, gv0.z, gv0.w, gv1.x, gv1.y, gv1.z, gv1.w};
    float bb[8] = {be0.x, be0.y, be0.z, be0.w, be1.x, be1.y, be1.z, be1.w};
    float y[8];
#pragma unroll
    for (int j = 0; j < 8; ++j) y[j] = (x[j] - mean) * rs * gg[j] + bb[j];
    if (MODE == 2) {
        ((float4*)(yf + base))[0] = make_float4(y[0], y[1], y[2], y[3]);
        ((float4*)(yf + base))[1] = make_float4(y[4], y[5], y[6], y[7]);
        return;
    }
    uint4 r;
    r.x = pk2(y[0], y[1]); r.y = pk2(y[2], y[3]);
    r.z = pk2(y[4], y[5]); r.w = pk2(y[6], y[7]);
    *(uint4*)(yb + base) = r;
    if (MODE == 0) {
        float pv[8];
        unp8(*(const uint4*)(pos + base), pv);
        uint4 q;
        q.x = pk2(y[0] + pv[0], y[1] + pv[1]);
        q.y = pk2(y[2] + pv[2], y[3] + pv[3]);
        q.z = pk2(y[4] + pv[4], y[5] + pv[5]);
        q.w = pk2(y[6] + pv[6], y[7] + pv[7]);
        *(uint4*)(qb + base) = q;
    }
}

// ---------------------------------------------------------------- host
extern "C" void kernel_launch(void* const* d_in, const int* in_sizes, int n_in,
                              void* d_out, int out_size, void* d_ws, size_t ws_size,
                              hipStream_t stream) {
    (void)in_sizes; (void)n_in; (void)out_size; (void)ws_size;
    const float* tgt      = (const float*)d_in[0];
    const float* memory   = (const float*)d_in[1];
    const float* tgt_pos  = (const float*)d_in[2];
    const float* mem_pos  = (const float*)d_in[3];
    const int*   tgt_mask = (const int*)d_in[4];
    const int*   mem_mask = (const int*)d_in[5];
    const float* sa_b[4] = {(const float*)d_in[7], (const float*)d_in[9],
                            (const float*)d_in[11], (const float*)d_in[13]};
    const float* ca_b[4] = {(const float*)d_in[15], (const float*)d_in[17],
                            (const float*)d_in[19], (const float*)d_in[21]};
    const float* ln1_g = (const float*)d_in[22]; const float* ln1_b = (const float*)d_in[23];
    const float* ln2_g = (const float*)d_in[24]; const float* ln2_b = (const float*)d_in[25];
    const float* ln3_g = (const float*)d_in[26]; const float* ln3_b = (const float*)d_in[27];
    const float* mlp_b1 = (const float*)d_in[29];
    const float* mlp_b2 = (const float*)d_in[31];

    const size_t MiB = 1024 * 1024;
    char* ws = (char*)d_ws;           // ws_size = 256 MiB
    u16*  WT  = (u16*)(ws + 0);
    u32*  MBS = (u32*)(ws + 8 * MiB);
    u32*  MBC = (u32*)(ws + 8 * MiB + 512 * 1024);
    u16*  QIN = (u16*)(ws + 9 * MiB);
    u16*  TGTB= (u16*)(ws + 13 * MiB);
    u16*  MEMB= (u16*)(ws + 17 * MiB);
    u16*  MKB = (u16*)(ws + 21 * MiB);
    u16*  QM  = (u16*)(ws + 25 * MiB);
    u16*  KMS = (u16*)(ws + 29 * MiB);
    u16*  KMC = (u16*)(ws + 33 * MiB);
    u16*  VTS = (u16*)(ws + 37 * MiB);
    u16*  VTC = (u16*)(ws + 41 * MiB);
    u16*  ATNB= (u16*)(ws + 45 * MiB);
    u16*  P1B = (u16*)(ws + 49 * MiB);     // 4 MiB bf16 GEMM partial 1
    u16*  X1B = (u16*)(ws + 53 * MiB);     // 4 MiB bf16 residual
    u16*  MQB = (u16*)(ws + 57 * MiB);     // 4 MiB
    u16*  X2B = (u16*)(ws + 61 * MiB);     // 4 MiB bf16 residual + FFN input
    u16*  TPB = (u16*)(ws + 65 * MiB);     // 4 MiB bf16 tgt_pos
    u16*  P2B = (u16*)(ws + 69 * MiB);     // 4 MiB bf16 GEMM partial 2
    u16*  FFH = (u16*)(ws + 9 * MiB);      // 16 MiB, aliases QIN..MKB (dead by FFN)
    u16*  OPB = (u16*)(ws + 96 * MiB);     // 2 x 4 MiB bf16 attn partials
    float2* MLB = (float2*)(ws + 120 * MiB); // 512 KiB m,l

    u16* wt[10];
    for (int z = 0; z < 8; ++z) wt[z] = WT + (size_t)z * 262144;
    wt[8] = WT + 2097152;
    wt[9] = WT + 3145728;

    ProArgs pa;
    pa.w[0] = (const float*)d_in[6];  pa.w[1] = (const float*)d_in[8];
    pa.w[2] = (const float*)d_in[10]; pa.w[3] = (const float*)d_in[12];
    pa.w[4] = (const float*)d_in[14]; pa.w[5] = (const float*)d_in[16];
    pa.w[6] = (const float*)d_in[18]; pa.w[7] = (const float*)d_in[20];
    pa.w[8] = (const float*)d_in[28]; pa.w[9] = (const float*)d_in[30];
    pa.wtbase = WT;
    pa.tgt = (const float4*)tgt; pa.tpos = (const float4*)tgt_pos;
    pa.mem = (const float4*)memory; pa.mpos = (const float4*)mem_pos;
    pa.qin = (ushort4*)QIN; pa.tgtb = (ushort4*)TGTB;
    pa.memb = (ushort4*)MEMB; pa.mkb = (ushort4*)MKB;
    pa.tposb = (ushort4*)TPB;
    pa.m1 = (const int4*)tgt_mask; pa.m2 = (const int4*)mem_mask;
    pa.o1 = MBS; pa.o2 = MBC;
    prologue_kernel<<<16384, 256, 0, stream>>>(pa);

    const float QSC = 0.125f * 1.44269504f;   // fold log2e into Q (exp2 softmax)
    GemmArgs5 ga;
    // Batched: SA Q,K,V + CA K,V
    ga.s[0] = {QIN,  wt[0], sa_b[0], QM,  QSC, 0, 0, 512};
    ga.s[1] = {QIN,  wt[1], sa_b[1], KMS, 1.f, 0, 0, 512};
    ga.s[2] = {TGTB, wt[2], sa_b[2], VTS, 1.f, 3, 0, 512};
    ga.s[3] = {MKB,  wt[5], ca_b[1], KMC, 1.f, 0, 0, 512};
    ga.s[4] = {MEMB, wt[6], ca_b[2], VTC, 1.f, 3, 0, 512};
    gemm_kernel<128, 64><<<dim3(8, 32, 5), 256, 0, stream>>>(ga, 4096, 512, 512);
    attn_part_kernel<<<dim3(8, 8, 8), 512, 0, stream>>>(QM, KMS, VTS, MBS, OPB, MLB);
    attn_combine_kernel<<<1024, 256, 0, stream>>>(OPB, MLB, ATNB);
    // SA O-proj, K-split x2 -> P1,P2
    ga.s[0] = {ATNB, wt[3], sa_b[3], P1B, 1.f, 0, 0,   256};
    ga.s[1] = {ATNB, wt[3], nullptr, P2B, 1.f, 0, 256, 256};
    ga.s[2] = ga.s[0]; ga.s[3] = ga.s[0]; ga.s[4] = ga.s[0];
    gemm_kernel<64, 64><<<dim3(8, 64, 2), 256, 0, stream>>>(ga, 4096, 512, 512);
    ln_kernel<0><<<1024, 256, 0, stream>>>(TGTB, P1B, P2B, ln1_g, ln1_b, TPB, X1B, MQB, nullptr);

    // CA Q projection
    ga.s[0] = {MQB, wt[4], ca_b[0], QM, QSC, 0, 0, 512};
    ga.s[1] = ga.s[0]; ga.s[2] = ga.s[0]; ga.s[3] = ga.s[0]; ga.s[4] = ga.s[0];
    gemm_kernel<64, 64><<<dim3(8, 64, 1), 256, 0, stream>>>(ga, 4096, 512, 512);
    attn_part_kernel<<<dim3(8, 8, 8), 512, 0, stream>>>(QM, KMC, VTC, MBC, OPB, MLB);
    attn_combine_kernel<<<1024, 256, 0, stream>>>(OPB, MLB, ATNB);
    // CA O-proj, K-split x2
    ga.s[0] = {ATNB, wt[7], ca_b[3], P1B, 1.f, 0, 0,   256};
    ga.s[1] = {ATNB, wt[7], nullptr, P2B, 1.f, 0, 256, 256};
    ga.s[2] = ga.s[0]; ga.s[3] = ga.s[0]; ga.s[4] = ga.s[0];
    gemm_kernel<64, 64><<<dim3(8, 64, 2), 256, 0, stream>>>(ga, 4096, 512, 512);
    ln_kernel<1><<<1024, 256, 0, stream>>>(X1B, P1B, P2B, ln2_g, ln2_b, nullptr, X2B, nullptr, nullptr);

    // FFN1 (relu)
    ga.s[0] = {X2B, wt[8], mlp_b1, FFH, 1.f, 1, 0, 512};
    ga.s[1] = ga.s[0]; ga.s[2] = ga.s[0]; ga.s[3] = ga.s[0]; ga.s[4] = ga.s[0];
    gemm_kernel<128, 64><<<dim3(32, 32, 1), 256, 0, stream>>>(ga, 4096, 2048, 512);
    // FFN2, K-split x2 (K=2048)
    ga.s[0] = {FFH, wt[9], mlp_b2, P1B, 1.f, 0, 0,    1024};
    ga.s[1] = {FFH, wt[9], nullptr, P2B, 1.f, 0, 1024, 1024};
    ga.s[2] = ga.s[0]; ga.s[3] = ga.s[0]; ga.s[4] = ga.s[0];
    gemm_kernel<64, 64><<<dim3(8, 64, 2), 256, 0, stream>>>(ga, 4096, 512, 2048);
    ln_kernel<2><<<1024, 256, 0, stream>>>(X2B, P1B, P2B, ln3_g, ln3_b, nullptr,
                                           nullptr, nullptr, (float*)d_out);
}